// Round 4
// baseline (262.687 us; speedup 1.0000x reference)
//
#include <hip/hip_runtime.h>
#include <stdint.h>

// YatCausalAttention on MI355X (gfx950).
// Inputs FP32, output FP32 (reference dtypes). Intermediates FP16 via f16 MFMA
// (11-bit mantissa: 8x tighter than bf16, same rate/bytes).
// Pipeline: transpose+cvt(w_qkv), transpose+cvt(w_out) -> gemm<A_FP32>(x,wqkvT)
//           -> qkv(fp16) -> flash-style yat attention -> gemm<fp16,OUT_F32> -> out.
// ws (fp16 elems): wqkvT 3072*1024 | woT 1024*1024 | qkv 4096*3072 | attn 4096*1024 = 40 MB
// R4: d_out re-typed fp32 (R3's 4.22>max|ref| error = bf16 u16s written into an
// fp32 buffer -> positional scramble + zero tail). bf16 -> fp16 for margin.

#define TSEQ 2048
#define BATCH 2

typedef _Float16 f16x8 __attribute__((ext_vector_type(8)));
typedef float f32x4 __attribute__((ext_vector_type(4)));

#define MFMA16(a, b, c) __builtin_amdgcn_mfma_f32_16x16x32_f16(a, b, c, 0, 0, 0)

__device__ __forceinline__ unsigned short f2h(float f) {
  union { _Float16 h; unsigned short u; } v;
  v.h = (_Float16)f;
  return v.u;
}
__device__ __forceinline__ float h2f(unsigned short u) {
  union { unsigned short u; _Float16 h; } v;
  v.u = u;
  return (float)v.h;
}
__device__ __forceinline__ unsigned int pack2h(float lo, float hi) {
  return (unsigned int)f2h(lo) | ((unsigned int)f2h(hi) << 16);
}
__device__ __forceinline__ float sumsq_u32(unsigned int u) {
  float lo = h2f(u & 0xffffu);
  float hi = h2f(u >> 16);
  return lo * lo + hi * hi;
}

// ------------- weight transpose+convert: src[K][N] (fp32) -> dst[N][K] (fp16) -------------
__global__ __launch_bounds__(256) void transpose_w(const float* __restrict__ src,
                                                   unsigned short* __restrict__ dst,
                                                   int K, int N) {
  __shared__ unsigned short tile[32][33];
  const int tx = threadIdx.x, ty = threadIdx.y;           // (32,8)
  const int nb = blockIdx.x * 32, kb = blockIdx.y * 32;
#pragma unroll
  for (int i = 0; i < 4; i++)
    tile[ty + 8 * i][tx] = f2h(src[(size_t)(kb + ty + 8 * i) * N + nb + tx]);
  __syncthreads();
#pragma unroll
  for (int i = 0; i < 4; i++)
    dst[(size_t)(nb + ty + 8 * i) * K + kb + tx] = tile[tx][ty + 8 * i];
}

// ------------- C[M][N] = A[M][K] * Bt[N][K]^T + bias[N]  (fp32 acc) -------------
// 128x128 tile, BK=32, 4 waves each 64x64 as 4x4 of 16x16x32 f16 MFMA.
// A fp32 (converted during staging) when A_FP32 else fp16. Bt fp16. bias fp32.
// C is fp32 when OUT_F32, else fp16.
template <bool A_FP32, bool OUT_F32>
__global__ __launch_bounds__(256) void gemm_bt(const void* __restrict__ Ap,
                                               const unsigned short* __restrict__ Bt,
                                               const float* __restrict__ bias,
                                               void* __restrict__ Cp,
                                               int M, int N, int K) {
  __shared__ __attribute__((aligned(16))) unsigned short Atile[128 * 32];
  __shared__ __attribute__((aligned(16))) unsigned short Btile[128 * 32];
  const int tid = threadIdx.x;
  const int w = tid >> 6, lane = tid & 63;
  const int quad = lane >> 4, l15 = lane & 15;
  const int m0 = blockIdx.y * 128, n0 = blockIdx.x * 128;
  const int wr = w >> 1, wc = w & 1;
  (void)M;
  // chunk ids: c in [0,512); row = c>>2, 8-elem k-chunk = c&3; LDS elem off = c*8
  const int c0 = tid, c1 = 256 + tid;
  const int r0 = c0 >> 2, k0 = (c0 & 3) * 8;
  const int r1 = c1 >> 2, k1 = (c1 & 3) * 8;
  f32x4 acc[4][4] = {};
  for (int kt = 0; kt < K; kt += 32) {
    // global loads first (overlap with previous iteration's MFMA tail)
    uint4 a0, a1;
    if constexpr (A_FP32) {
      const float* A = (const float*)Ap;
      const float4 f00 = *(const float4*)(A + (size_t)(m0 + r0) * K + kt + k0);
      const float4 f01 = *(const float4*)(A + (size_t)(m0 + r0) * K + kt + k0 + 4);
      const float4 f10 = *(const float4*)(A + (size_t)(m0 + r1) * K + kt + k1);
      const float4 f11 = *(const float4*)(A + (size_t)(m0 + r1) * K + kt + k1 + 4);
      a0.x = pack2h(f00.x, f00.y); a0.y = pack2h(f00.z, f00.w);
      a0.z = pack2h(f01.x, f01.y); a0.w = pack2h(f01.z, f01.w);
      a1.x = pack2h(f10.x, f10.y); a1.y = pack2h(f10.z, f10.w);
      a1.z = pack2h(f11.x, f11.y); a1.w = pack2h(f11.z, f11.w);
    } else {
      const unsigned short* A = (const unsigned short*)Ap;
      a0 = *(const uint4*)(A + (size_t)(m0 + r0) * K + kt + k0);
      a1 = *(const uint4*)(A + (size_t)(m0 + r1) * K + kt + k1);
    }
    const uint4 b0 = *(const uint4*)(Bt + (size_t)(n0 + r0) * K + kt + k0);
    const uint4 b1 = *(const uint4*)(Bt + (size_t)(n0 + r1) * K + kt + k1);
    __syncthreads();  // previous iteration's fragment reads done
    *(uint4*)&Atile[c0 * 8] = a0;
    *(uint4*)&Atile[c1 * 8] = a1;
    *(uint4*)&Btile[c0 * 8] = b0;
    *(uint4*)&Btile[c1 * 8] = b1;
    __syncthreads();
    f16x8 af[4], bfr[4];
#pragma unroll
    for (int i = 0; i < 4; i++)
      af[i] = *(const f16x8*)&Atile[(wr * 64 + i * 16 + l15) * 32 + quad * 8];
#pragma unroll
    for (int j = 0; j < 4; j++)
      bfr[j] = *(const f16x8*)&Btile[(wc * 64 + j * 16 + l15) * 32 + quad * 8];
#pragma unroll
    for (int i = 0; i < 4; i++)
#pragma unroll
      for (int j = 0; j < 4; j++)
        acc[i][j] = MFMA16(af[i], bfr[j], acc[i][j]);
  }
  // epilogue: C/D layout col=lane&15, row=quad*4+reg
#pragma unroll
  for (int j = 0; j < 4; j++) {
    const int n = n0 + wc * 64 + j * 16 + l15;
    const float bv = bias[n];
#pragma unroll
    for (int i = 0; i < 4; i++) {
      const int mb = m0 + wr * 64 + i * 16 + quad * 4;
#pragma unroll
      for (int r = 0; r < 4; r++) {
        if constexpr (OUT_F32)
          ((float*)Cp)[(size_t)(mb + r) * N + n] = acc[i][j][r] + bv;
        else
          ((unsigned short*)Cp)[(size_t)(mb + r) * N + n] = f2h(acc[i][j][r] + bv);
      }
    }
  }
}

// ---------------- Yat causal flash attention (fp16 in/out, fp32 math) ----------------
// grid: (B*H, T/64). Block 256 = 4 waves; wave w owns q rows [16w,16w+16).
// score = dot^2 / (qsq + ksq - 2 dot + 1e-6), causal, online softmax.
// PV computed as O^T = V^T * P^T so rescale factor is per-lane uniform.
__global__ __launch_bounds__(256) void yat_attn(const unsigned short* __restrict__ qkv,
                                                unsigned short* __restrict__ outp) {
  __shared__ __attribute__((aligned(16))) unsigned short Qp[64 * 72];  // [q][d] pad 72
  __shared__ __attribute__((aligned(16))) unsigned short Kp[64 * 72];  // [t][d]
  __shared__ __attribute__((aligned(16))) unsigned short Vt[64 * 72];  // [d][t]
  __shared__ __attribute__((aligned(16))) unsigned short Pl[64 * 72];  // [q][t]
  __shared__ float qsq[64], ksq[64], bcast[64];
  const int tid = threadIdx.x;
  const int w = tid >> 6, lane = tid & 63;
  const int quad = lane >> 4, l15 = lane & 15;
  const int bh = blockIdx.x, b = bh >> 4, h = bh & 15;
  const int qt = 31 - blockIdx.y;  // long blocks first (load balance)
  const unsigned short* base = qkv + (size_t)b * TSEQ * 3072 + h * 64;
  const int t = tid >> 2, dc = (tid & 3) * 16;  // staging: row t, 16 d's per thread

  {  // stage Q tile + row sums of squares (from the SAME rounded values MFMA sees)
    const unsigned short* g = base + (size_t)(qt * 64 + t) * 3072 + dc;
    uint4 v0 = *(const uint4*)g;
    uint4 v1 = *(const uint4*)(g + 8);
    *(uint4*)&Qp[t * 72 + dc] = v0;
    *(uint4*)&Qp[t * 72 + dc + 8] = v1;
    float s = sumsq_u32(v0.x) + sumsq_u32(v0.y) + sumsq_u32(v0.z) + sumsq_u32(v0.w) +
              sumsq_u32(v1.x) + sumsq_u32(v1.y) + sumsq_u32(v1.z) + sumsq_u32(v1.w);
    s += __shfl_xor(s, 1);
    s += __shfl_xor(s, 2);
    if ((tid & 3) == 0) qsq[t] = s;
  }

  f32x4 accO[4] = {};                       // O^T: lane q = 16w+l15, d = 16i+quad*4+r
  float m_r[4] = {0.f, 0.f, 0.f, 0.f};      // scores >= 0 so 0 is a valid init max
  float l_r[4] = {0.f, 0.f, 0.f, 0.f};

  for (int kt = 0; kt <= qt; kt++) {
    __syncthreads();
    {  // stage K [t][d], V^T [d][t], ksq
      const unsigned short* gk = base + 1024 + (size_t)(kt * 64 + t) * 3072 + dc;
      uint4 k0 = *(const uint4*)gk;
      uint4 k1 = *(const uint4*)(gk + 8);
      *(uint4*)&Kp[t * 72 + dc] = k0;
      *(uint4*)&Kp[t * 72 + dc + 8] = k1;
      float s = sumsq_u32(k0.x) + sumsq_u32(k0.y) + sumsq_u32(k0.z) + sumsq_u32(k0.w) +
                sumsq_u32(k1.x) + sumsq_u32(k1.y) + sumsq_u32(k1.z) + sumsq_u32(k1.w);
      s += __shfl_xor(s, 1);
      s += __shfl_xor(s, 2);
      if ((tid & 3) == 0) ksq[t] = s;
      const unsigned short* gv = base + 2048 + (size_t)(kt * 64 + t) * 3072 + dc;
      uint4 u0 = *(const uint4*)gv;
      uint4 u1 = *(const uint4*)(gv + 8);
      const unsigned int uu[8] = {u0.x, u0.y, u0.z, u0.w, u1.x, u1.y, u1.z, u1.w};
#pragma unroll
      for (int e = 0; e < 8; e++) {
        Vt[(dc + 2 * e) * 72 + t] = (unsigned short)(uu[e] & 0xffffu);
        Vt[(dc + 2 * e + 1) * 72 + t] = (unsigned short)(uu[e] >> 16);
      }
    }
    __syncthreads();

    // S = Q K^T : wave's 16 q rows x 64 keys
    f32x4 accS[4] = {};
    const f16x8 aq0 = *(const f16x8*)&Qp[(w * 16 + l15) * 72 + quad * 8];
    const f16x8 aq1 = *(const f16x8*)&Qp[(w * 16 + l15) * 72 + 32 + quad * 8];
#pragma unroll
    for (int nt = 0; nt < 4; nt++) {
      const f16x8 bk0 = *(const f16x8*)&Kp[(nt * 16 + l15) * 72 + quad * 8];
      const f16x8 bk1 = *(const f16x8*)&Kp[(nt * 16 + l15) * 72 + 32 + quad * 8];
      accS[nt] = MFMA16(aq0, bk0, accS[nt]);
      accS[nt] = MFMA16(aq1, bk1, accS[nt]);
    }
    const bool diag = (kt == qt);
    float pval[4][4];
    float tmax[4] = {-1e30f, -1e30f, -1e30f, -1e30f};
#pragma unroll
    for (int nt = 0; nt < 4; nt++) {
#pragma unroll
      for (int r = 0; r < 4; r++) {
        const int ql = w * 16 + quad * 4 + r;   // C-layout row
        const int tl = nt * 16 + l15;           // C-layout col
        const float d = accS[nt][r];
        const float den = qsq[ql] + ksq[tl] - 2.f * d + 1e-6f;
        float s = d * d / den;
        if (diag && tl > ql) s = -1e30f;
        pval[nt][r] = s;
        tmax[r] = fmaxf(tmax[r], s);
      }
    }
#pragma unroll
    for (int r = 0; r < 4; r++) {
      tmax[r] = fmaxf(tmax[r], __shfl_xor(tmax[r], 1));
      tmax[r] = fmaxf(tmax[r], __shfl_xor(tmax[r], 2));
      tmax[r] = fmaxf(tmax[r], __shfl_xor(tmax[r], 4));
      tmax[r] = fmaxf(tmax[r], __shfl_xor(tmax[r], 8));
    }
    float alpha[4];
#pragma unroll
    for (int r = 0; r < 4; r++) {
      const float mn = fmaxf(m_r[r], tmax[r]);
      alpha[r] = __expf(m_r[r] - mn);
      m_r[r] = mn;
    }
#pragma unroll
    for (int nt = 0; nt < 4; nt++)
#pragma unroll
      for (int r = 0; r < 4; r++)
        pval[nt][r] = __expf(pval[nt][r] - m_r[r]);
#pragma unroll
    for (int r = 0; r < 4; r++) {
      float su = pval[0][r] + pval[1][r] + pval[2][r] + pval[3][r];
      su += __shfl_xor(su, 1);
      su += __shfl_xor(su, 2);
      su += __shfl_xor(su, 4);
      su += __shfl_xor(su, 8);
      l_r[r] = l_r[r] * alpha[r] + su;
    }
#pragma unroll
    for (int nt = 0; nt < 4; nt++)
#pragma unroll
      for (int r = 0; r < 4; r++)
        Pl[(w * 16 + quad * 4 + r) * 72 + nt * 16 + l15] = f2h(pval[nt][r]);
    if (l15 == 0) {
#pragma unroll
      for (int r = 0; r < 4; r++) bcast[w * 16 + quad * 4 + r] = alpha[r];
    }
    __syncthreads();

    // rescale O^T (per-lane uniform alpha) then O^T += V^T P^T
    const float am = bcast[w * 16 + l15];
#pragma unroll
    for (int i = 0; i < 4; i++) {
      accO[i][0] *= am; accO[i][1] *= am; accO[i][2] *= am; accO[i][3] *= am;
    }
    const f16x8 bp0 = *(const f16x8*)&Pl[(w * 16 + l15) * 72 + quad * 8];
    const f16x8 bp1 = *(const f16x8*)&Pl[(w * 16 + l15) * 72 + 32 + quad * 8];
#pragma unroll
    for (int i = 0; i < 4; i++) {
      const f16x8 av0 = *(const f16x8*)&Vt[(i * 16 + l15) * 72 + quad * 8];
      const f16x8 av1 = *(const f16x8*)&Vt[(i * 16 + l15) * 72 + 32 + quad * 8];
      accO[i] = MFMA16(av0, bp0, accO[i]);
      accO[i] = MFMA16(av1, bp1, accO[i]);
    }
  }

  // finalize: divide by l, transpose O^T -> O through LDS, coalesced 16B stores
  __syncthreads();
  if (l15 == 0) {
#pragma unroll
    for (int r = 0; r < 4; r++) bcast[w * 16 + quad * 4 + r] = l_r[r];
  }
  __syncthreads();
  const float linv = 1.0f / bcast[w * 16 + l15];
#pragma unroll
  for (int i = 0; i < 4; i++)
#pragma unroll
    for (int r = 0; r < 4; r++)
      Qp[(w * 16 + l15) * 72 + i * 16 + quad * 4 + r] = f2h(accO[i][r] * linv);
  __syncthreads();
  {
    uint4 o0 = *(const uint4*)&Qp[t * 72 + dc];
    uint4 o1 = *(const uint4*)&Qp[t * 72 + dc + 8];
    unsigned short* g = outp + (size_t)(b * TSEQ + qt * 64 + t) * 1024 + h * 64 + dc;
    *(uint4*)g = o0;
    *(uint4*)(g + 8) = o1;
  }
}

extern "C" void kernel_launch(void* const* d_in, const int* in_sizes, int n_in,
                              void* d_out, int out_size, void* d_ws, size_t ws_size,
                              hipStream_t stream) {
  (void)in_sizes; (void)n_in; (void)out_size; (void)ws_size;
  const float* x     = (const float*)d_in[0];  // [2,2048,1024] fp32
  const float* w_qkv = (const float*)d_in[1];  // [1024,3072]   fp32
  const float* b_qkv = (const float*)d_in[2];  // [3072]        fp32
  const float* w_out = (const float*)d_in[3];  // [1024,1024]   fp32
  const float* b_out = (const float*)d_in[4];  // [1024]        fp32
  float* out = (float*)d_out;                  // [2,2048,1024] fp32

  unsigned short* wqkvT  = (unsigned short*)d_ws;                    // [3072][1024] fp16
  unsigned short* woT    = wqkvT + (size_t)3072 * 1024;              // [1024][1024] fp16
  unsigned short* qkvws  = woT + (size_t)1024 * 1024;                // [4096][3072] fp16
  unsigned short* attnws = qkvws + (size_t)4096 * 3072;              // [4096][1024] fp16

  transpose_w<<<dim3(3072 / 32, 1024 / 32), dim3(32, 8), 0, stream>>>(w_qkv, wqkvT, 1024, 3072);
  transpose_w<<<dim3(1024 / 32, 1024 / 32), dim3(32, 8), 0, stream>>>(w_out, woT, 1024, 1024);
  gemm_bt<true, false><<<dim3(3072 / 128, 4096 / 128), 256, 0, stream>>>(x, wqkvT, b_qkv, qkvws, 4096, 3072, 1024);
  yat_attn<<<dim3(BATCH * 16, TSEQ / 64), 256, 0, stream>>>(qkvws, attnws);
  gemm_bt<false, true><<<dim3(1024 / 128, 4096 / 128), 256, 0, stream>>>(attnws, woT, b_out, out, 4096, 1024, 1024);
}

// Round 5
// 246.428 us; speedup vs baseline: 1.0660x; 1.0660x over previous
//
#include <hip/hip_runtime.h>
#include <stdint.h>

// YatCausalAttention on MI355X (gfx950).
// Inputs FP32, output FP32. Intermediates FP16 via f16 MFMA, fp32 accum.
// Pipeline: cvt_x(fp32->fp16) -> transpose+cvt weights -> gemm(async-LDS m97)
//           -> qkv(fp16) -> yat flash attention (paired q-tiles) -> gemm -> out.
// ws (fp16 elems): wqkvT 3072*1024 | woT 1024*1024 | qkv 4096*3072 | xh/attn 4096*1024 = 40 MB
//   (xh aliases attnws: xh dead after gemm1, attnws born at yat_attn - same stream, serialized)
// R5: rcp instead of IEEE div in softmax; Vt staged via transposed u32 loads +
// 2x ds_write_b128 (was 16x 8-way-conflicted ds_write_u16); qt-paired blocks
// {31-y, y} = uniform 33 iters/block; gemms use global_load_lds width=16 (m97).

#define TSEQ 2048
#define BATCH 2

typedef _Float16 f16x8 __attribute__((ext_vector_type(8)));
typedef float f32x4 __attribute__((ext_vector_type(4)));

#define MFMA16(a, b, c) __builtin_amdgcn_mfma_f32_16x16x32_f16(a, b, c, 0, 0, 0)

__device__ __forceinline__ unsigned short f2h(float f) {
  union { _Float16 h; unsigned short u; } v;
  v.h = (_Float16)f;
  return v.u;
}
__device__ __forceinline__ float h2f(unsigned short u) {
  union { unsigned short u; _Float16 h; } v;
  v.u = u;
  return (float)v.h;
}
__device__ __forceinline__ unsigned int pack2h(float lo, float hi) {
  return (unsigned int)f2h(lo) | ((unsigned int)f2h(hi) << 16);
}
__device__ __forceinline__ float sumsq_u32(unsigned int u) {
  float lo = h2f(u & 0xffffu);
  float hi = h2f(u >> 16);
  return lo * lo + hi * hi;
}
__device__ __forceinline__ void async_ld16(const void* g, const void* l) {
  __builtin_amdgcn_global_load_lds((const __attribute__((address_space(1))) void*)g,
                                   (__attribute__((address_space(3))) void*)l,
                                   16, 0, 0);
}

// ---------------- x: fp32 -> fp16, 8 elems/thread ----------------
__global__ __launch_bounds__(256) void cvt_x(const float* __restrict__ src,
                                             unsigned short* __restrict__ dst) {
  const int i = (blockIdx.x * 256 + threadIdx.x) * 8;
  const float4 a = *(const float4*)(src + i);
  const float4 b = *(const float4*)(src + i + 4);
  uint4 o;
  o.x = pack2h(a.x, a.y); o.y = pack2h(a.z, a.w);
  o.z = pack2h(b.x, b.y); o.w = pack2h(b.z, b.w);
  *(uint4*)(dst + i) = o;
}

// ------------- weight transpose+convert: src[K][N] (fp32) -> dst[N][K] (fp16) -------------
__global__ __launch_bounds__(256) void transpose_w(const float* __restrict__ src,
                                                   unsigned short* __restrict__ dst,
                                                   int K, int N) {
  __shared__ unsigned short tile[32][33];
  const int tx = threadIdx.x, ty = threadIdx.y;           // (32,8)
  const int nb = blockIdx.x * 32, kb = blockIdx.y * 32;
#pragma unroll
  for (int i = 0; i < 4; i++)
    tile[ty + 8 * i][tx] = f2h(src[(size_t)(kb + ty + 8 * i) * N + nb + tx]);
  __syncthreads();
#pragma unroll
  for (int i = 0; i < 4; i++)
    dst[(size_t)(nb + ty + 8 * i) * K + kb + tx] = tile[tx][ty + 8 * i];
}

// ------------- C[M][N] = A[M][K] * Bt[N][K]^T + bias[N]  (fp16 in, fp32 acc) -------------
// m97 structure: 128x128 tile, BK=32, global_load_lds width=16, 4 waves 4x4 MFMA.
template <bool OUT_F32>
__global__ __launch_bounds__(256) void gemm_bt(const unsigned short* __restrict__ A,
                                               const unsigned short* __restrict__ Bt,
                                               const float* __restrict__ bias,
                                               void* __restrict__ Cp,
                                               int N, int K) {
  __shared__ __attribute__((aligned(16))) unsigned short Atile[128 * 32];
  __shared__ __attribute__((aligned(16))) unsigned short Btile[128 * 32];
  const int tid = threadIdx.x;
  const int w = tid >> 6, lane = tid & 63;
  const int quad = lane >> 4, l15 = lane & 15;
  const int m0 = blockIdx.y * 128, n0 = blockIdx.x * 128;
  const int wr = w >> 1, wc = w & 1;
  f32x4 acc[4][4] = {};
  for (int kt = 0; kt < K; kt += 32) {
    __syncthreads();  // previous iteration's fragment reads complete
#pragma unroll
    for (int it = 0; it < 2; it++) {
      const int c = it * 256 + tid;       // chunk: row = c>>2, 8-elem k-chunk = c&3
      const int row = c >> 2, kc = c & 3;
      async_ld16(A + (size_t)(m0 + row) * K + kt + kc * 8,
                 &Atile[(size_t)(it * 256 + w * 64) * 8]);   // wave-uniform LDS base
      async_ld16(Bt + (size_t)(n0 + row) * K + kt + kc * 8,
                 &Btile[(size_t)(it * 256 + w * 64) * 8]);
    }
    __syncthreads();  // vmcnt(0) drain lands the async copies
    f16x8 af[4], bfr[4];
#pragma unroll
    for (int i = 0; i < 4; i++)
      af[i] = *(const f16x8*)&Atile[(wr * 64 + i * 16 + l15) * 32 + quad * 8];
#pragma unroll
    for (int j = 0; j < 4; j++)
      bfr[j] = *(const f16x8*)&Btile[(wc * 64 + j * 16 + l15) * 32 + quad * 8];
#pragma unroll
    for (int i = 0; i < 4; i++)
#pragma unroll
      for (int j = 0; j < 4; j++)
        acc[i][j] = MFMA16(af[i], bfr[j], acc[i][j]);
  }
  // epilogue: C/D layout col=lane&15, row=quad*4+reg
#pragma unroll
  for (int j = 0; j < 4; j++) {
    const int n = n0 + wc * 64 + j * 16 + l15;
    const float bv = bias[n];
#pragma unroll
    for (int i = 0; i < 4; i++) {
      const int mb = m0 + wr * 64 + i * 16 + quad * 4;
#pragma unroll
      for (int r = 0; r < 4; r++) {
        if constexpr (OUT_F32)
          ((float*)Cp)[(size_t)(mb + r) * N + n] = acc[i][j][r] + bv;
        else
          ((unsigned short*)Cp)[(size_t)(mb + r) * N + n] = f2h(acc[i][j][r] + bv);
      }
    }
  }
}

// ---------------- Yat causal flash attention (fp16 in/out, fp32 math) ----------------
// grid: (B*H, 16). Block 256 = 4 waves; processes q-tiles {31-y, y} = 33 iters uniform.
// score = dot^2 * rcp(qsq + ksq - 2 dot + 1e-6), causal, online softmax.
// PV as O^T = V^T * P^T (rescale per-lane uniform). V^T staged via transposed
// u32 global loads + register repack -> 2x ds_write_b128 per thread.
__global__ __launch_bounds__(256) void yat_attn(const unsigned short* __restrict__ qkv,
                                                unsigned short* __restrict__ outp) {
  __shared__ __attribute__((aligned(16))) unsigned short Qp[64 * 72];  // [q][d] pad 72
  __shared__ __attribute__((aligned(16))) unsigned short Kp[64 * 72];  // [t][d]
  __shared__ __attribute__((aligned(16))) unsigned short Vt[64 * 72];  // [d][t]
  __shared__ __attribute__((aligned(16))) unsigned short Pl[64 * 72];  // [q][t]
  __shared__ float qsq[64], ksq[64], bcast[64];
  const int tid = threadIdx.x;
  const int w = tid >> 6, lane = tid & 63;
  const int quad = lane >> 4, l15 = lane & 15;
  const int bh = blockIdx.x, b = bh >> 4, h = bh & 15;
  const unsigned short* base = qkv + (size_t)b * TSEQ * 3072 + h * 64;
  const int t = tid >> 2, dc = (tid & 3) * 16;   // K/Q staging: row t, 16 d's
  const int d0 = tid & 31, tg8 = tid >> 5;       // V staging: 2 d-rows, 8 t's

#pragma unroll 1
  for (int half = 0; half < 2; half++) {
    const int qt = half ? (int)blockIdx.y : 31 - (int)blockIdx.y;
    __syncthreads();  // prev half's O-store read Qp
    {  // stage Q tile + row sums of squares (same rounded values MFMA sees)
      const unsigned short* g = base + (size_t)(qt * 64 + t) * 3072 + dc;
      uint4 v0 = *(const uint4*)g;
      uint4 v1 = *(const uint4*)(g + 8);
      *(uint4*)&Qp[t * 72 + dc] = v0;
      *(uint4*)&Qp[t * 72 + dc + 8] = v1;
      float s = sumsq_u32(v0.x) + sumsq_u32(v0.y) + sumsq_u32(v0.z) + sumsq_u32(v0.w) +
                sumsq_u32(v1.x) + sumsq_u32(v1.y) + sumsq_u32(v1.z) + sumsq_u32(v1.w);
      s += __shfl_xor(s, 1);
      s += __shfl_xor(s, 2);
      if ((tid & 3) == 0) qsq[t] = s;
    }

    f32x4 accO[4] = {};                    // O^T: lane q = 16w+l15, d = 16i+quad*4+r
    float m_r[4] = {0.f, 0.f, 0.f, 0.f};   // scores >= 0 so 0 is a valid init max
    float l_r[4] = {0.f, 0.f, 0.f, 0.f};

    for (int kt = 0; kt <= qt; kt++) {
      __syncthreads();
      {  // stage K [t][d] + ksq
        const unsigned short* gk = base + 1024 + (size_t)(kt * 64 + t) * 3072 + dc;
        uint4 k0 = *(const uint4*)gk;
        uint4 k1 = *(const uint4*)(gk + 8);
        *(uint4*)&Kp[t * 72 + dc] = k0;
        *(uint4*)&Kp[t * 72 + dc + 8] = k1;
        float s = sumsq_u32(k0.x) + sumsq_u32(k0.y) + sumsq_u32(k0.z) + sumsq_u32(k0.w) +
                  sumsq_u32(k1.x) + sumsq_u32(k1.y) + sumsq_u32(k1.z) + sumsq_u32(k1.w);
        s += __shfl_xor(s, 1);
        s += __shfl_xor(s, 2);
        if ((tid & 3) == 0) ksq[t] = s;
      }
      {  // stage V^T [d][t]: transposed u32 loads, repack, 2x ds_write_b128
        const unsigned short* gv = base + 2048 + (size_t)(kt * 64 + tg8 * 8) * 3072 + 2 * d0;
        unsigned int vv[8];
#pragma unroll
        for (int s = 0; s < 8; s++)
          vv[s] = *(const unsigned int*)(gv + (size_t)s * 3072);
        uint4 LO, HI;
        LO.x = (vv[0] & 0xffffu) | (vv[1] << 16);
        LO.y = (vv[2] & 0xffffu) | (vv[3] << 16);
        LO.z = (vv[4] & 0xffffu) | (vv[5] << 16);
        LO.w = (vv[6] & 0xffffu) | (vv[7] << 16);
        HI.x = (vv[0] >> 16) | (vv[1] & 0xffff0000u);
        HI.y = (vv[2] >> 16) | (vv[3] & 0xffff0000u);
        HI.z = (vv[4] >> 16) | (vv[5] & 0xffff0000u);
        HI.w = (vv[6] >> 16) | (vv[7] & 0xffff0000u);
        *(uint4*)&Vt[(2 * d0) * 72 + tg8 * 8] = LO;
        *(uint4*)&Vt[(2 * d0 + 1) * 72 + tg8 * 8] = HI;
      }
      __syncthreads();

      // S = Q K^T : wave's 16 q rows x 64 keys
      f32x4 accS[4] = {};
      const f16x8 aq0 = *(const f16x8*)&Qp[(w * 16 + l15) * 72 + quad * 8];
      const f16x8 aq1 = *(const f16x8*)&Qp[(w * 16 + l15) * 72 + 32 + quad * 8];
#pragma unroll
      for (int nt = 0; nt < 4; nt++) {
        const f16x8 bk0 = *(const f16x8*)&Kp[(nt * 16 + l15) * 72 + quad * 8];
        const f16x8 bk1 = *(const f16x8*)&Kp[(nt * 16 + l15) * 72 + 32 + quad * 8];
        accS[nt] = MFMA16(aq0, bk0, accS[nt]);
        accS[nt] = MFMA16(aq1, bk1, accS[nt]);
      }
      const bool diag = (kt == qt);
      float pval[4][4];
      float tmax[4] = {0.f, 0.f, 0.f, 0.f};  // scores >= 0 (masked = 0 weight anyway)
#pragma unroll
      for (int nt = 0; nt < 4; nt++) {
#pragma unroll
        for (int r = 0; r < 4; r++) {
          const int ql = w * 16 + quad * 4 + r;   // C-layout row
          const int tl = nt * 16 + l15;           // C-layout col
          const float d = accS[nt][r];
          const float den = qsq[ql] + ksq[tl] - 2.f * d + 1e-6f;
          float s = d * d * __builtin_amdgcn_rcpf(den);
          if (diag && tl > ql) s = -1e30f;
          pval[nt][r] = s;
          tmax[r] = fmaxf(tmax[r], s);
        }
      }
#pragma unroll
      for (int r = 0; r < 4; r++) {
        tmax[r] = fmaxf(tmax[r], __shfl_xor(tmax[r], 1));
        tmax[r] = fmaxf(tmax[r], __shfl_xor(tmax[r], 2));
        tmax[r] = fmaxf(tmax[r], __shfl_xor(tmax[r], 4));
        tmax[r] = fmaxf(tmax[r], __shfl_xor(tmax[r], 8));
      }
      float alpha[4];
#pragma unroll
      for (int r = 0; r < 4; r++) {
        const float mn = fmaxf(m_r[r], tmax[r]);
        alpha[r] = __expf(m_r[r] - mn);
        m_r[r] = mn;
      }
#pragma unroll
      for (int nt = 0; nt < 4; nt++)
#pragma unroll
        for (int r = 0; r < 4; r++)
          pval[nt][r] = __expf(pval[nt][r] - m_r[r]);
#pragma unroll
      for (int r = 0; r < 4; r++) {
        float su = pval[0][r] + pval[1][r] + pval[2][r] + pval[3][r];
        su += __shfl_xor(su, 1);
        su += __shfl_xor(su, 2);
        su += __shfl_xor(su, 4);
        su += __shfl_xor(su, 8);
        l_r[r] = l_r[r] * alpha[r] + su;
      }
#pragma unroll
      for (int nt = 0; nt < 4; nt++)
#pragma unroll
        for (int r = 0; r < 4; r++)
          Pl[(w * 16 + quad * 4 + r) * 72 + nt * 16 + l15] = f2h(pval[nt][r]);
      if (l15 == 0) {
#pragma unroll
        for (int r = 0; r < 4; r++) bcast[w * 16 + quad * 4 + r] = alpha[r];
      }
      __syncthreads();

      // rescale O^T (per-lane uniform alpha) then O^T += V^T P^T
      const float am = bcast[w * 16 + l15];
#pragma unroll
      for (int i = 0; i < 4; i++) {
        accO[i][0] *= am; accO[i][1] *= am; accO[i][2] *= am; accO[i][3] *= am;
      }
      const f16x8 bp0 = *(const f16x8*)&Pl[(w * 16 + l15) * 72 + quad * 8];
      const f16x8 bp1 = *(const f16x8*)&Pl[(w * 16 + l15) * 72 + 32 + quad * 8];
#pragma unroll
      for (int i = 0; i < 4; i++) {
        const f16x8 av0 = *(const f16x8*)&Vt[(i * 16 + l15) * 72 + quad * 8];
        const f16x8 av1 = *(const f16x8*)&Vt[(i * 16 + l15) * 72 + 32 + quad * 8];
        accO[i] = MFMA16(av0, bp0, accO[i]);
        accO[i] = MFMA16(av1, bp1, accO[i]);
      }
    }

    // finalize: divide by l, transpose O^T -> O through LDS, coalesced 16B stores
    __syncthreads();
    if (l15 == 0) {
#pragma unroll
      for (int r = 0; r < 4; r++) bcast[w * 16 + quad * 4 + r] = l_r[r];
    }
    __syncthreads();
    const float linv = 1.0f / bcast[w * 16 + l15];
#pragma unroll
    for (int i = 0; i < 4; i++)
#pragma unroll
      for (int r = 0; r < 4; r++)
        Qp[(w * 16 + l15) * 72 + i * 16 + quad * 4 + r] = f2h(accO[i][r] * linv);
    __syncthreads();
    {
      uint4 o0 = *(const uint4*)&Qp[t * 72 + dc];
      uint4 o1 = *(const uint4*)&Qp[t * 72 + dc + 8];
      unsigned short* g = outp + (size_t)(b * TSEQ + qt * 64 + t) * 1024 + h * 64 + dc;
      *(uint4*)g = o0;
      *(uint4*)(g + 8) = o1;
    }
  }
}

extern "C" void kernel_launch(void* const* d_in, const int* in_sizes, int n_in,
                              void* d_out, int out_size, void* d_ws, size_t ws_size,
                              hipStream_t stream) {
  (void)in_sizes; (void)n_in; (void)out_size; (void)ws_size;
  const float* x     = (const float*)d_in[0];  // [2,2048,1024] fp32
  const float* w_qkv = (const float*)d_in[1];  // [1024,3072]   fp32
  const float* b_qkv = (const float*)d_in[2];  // [3072]        fp32
  const float* w_out = (const float*)d_in[3];  // [1024,1024]   fp32
  const float* b_out = (const float*)d_in[4];  // [1024]        fp32
  float* out = (float*)d_out;                  // [2,2048,1024] fp32

  unsigned short* wqkvT  = (unsigned short*)d_ws;                    // [3072][1024] fp16
  unsigned short* woT    = wqkvT + (size_t)3072 * 1024;              // [1024][1024] fp16
  unsigned short* qkvws  = woT + (size_t)1024 * 1024;                // [4096][3072] fp16
  unsigned short* xh     = qkvws + (size_t)4096 * 3072;              // [4096][1024] fp16
  unsigned short* attnws = xh;  // alias: xh dead after gemm1, attnws born at yat_attn

  cvt_x<<<dim3(4096 * 1024 / (256 * 8)), 256, 0, stream>>>(x, xh);
  transpose_w<<<dim3(3072 / 32, 1024 / 32), dim3(32, 8), 0, stream>>>(w_qkv, wqkvT, 1024, 3072);
  transpose_w<<<dim3(1024 / 32, 1024 / 32), dim3(32, 8), 0, stream>>>(w_out, woT, 1024, 1024);
  gemm_bt<false><<<dim3(3072 / 128, 4096 / 128), 256, 0, stream>>>(xh, wqkvT, b_qkv, qkvws, 3072, 1024);
  yat_attn<<<dim3(BATCH * 16, 16), 256, 0, stream>>>(qkvws, attnws);
  gemm_bt<true><<<dim3(1024 / 128, 4096 / 128), 256, 0, stream>>>(attnws, woT, b_out, out, 1024, 1024);
}

// Round 6
// 226.300 us; speedup vs baseline: 1.1608x; 1.0889x over previous
//
#include <hip/hip_runtime.h>
#include <stdint.h>

// YatCausalAttention on MI355X (gfx950).
// Inputs FP32, output FP32. Intermediates FP16 via f16 MFMA, fp32 accum.
// Pipeline: cvt_x(fp32->fp16) -> transpose+cvt weights -> gemm(async-LDS m97)
//           -> qkv(fp16) -> yat flash attention -> gemm -> out.
// ws (fp16 elems): wqkvT 3072*1024 | woT 1024*1024 | qkv 4096*3072 | xh/attn 4096*1024 = 40 MB
// R6: yat un-paired back to 1024 blocks (R5's pairing halved occupancy -> latency-bound:
// Occ 21%, VALU 42%, Mfma 6.5%). Dispatch-round qt map {31-y,y-8,39-y,y-16} gives every
// CU an exact 66-iteration sum. K/V register prefetch (kt+1 issued during kt compute)
// hides ~900cyc HBM latency. rcp softmax + Vt b128 repack retained from R5.

#define TSEQ 2048
#define BATCH 2

typedef _Float16 f16x8 __attribute__((ext_vector_type(8)));
typedef float f32x4 __attribute__((ext_vector_type(4)));

#define MFMA16(a, b, c) __builtin_amdgcn_mfma_f32_16x16x32_f16(a, b, c, 0, 0, 0)

__device__ __forceinline__ unsigned short f2h(float f) {
  union { _Float16 h; unsigned short u; } v;
  v.h = (_Float16)f;
  return v.u;
}
__device__ __forceinline__ float h2f(unsigned short u) {
  union { unsigned short u; _Float16 h; } v;
  v.u = u;
  return (float)v.h;
}
__device__ __forceinline__ unsigned int pack2h(float lo, float hi) {
  return (unsigned int)f2h(lo) | ((unsigned int)f2h(hi) << 16);
}
__device__ __forceinline__ float sumsq_u32(unsigned int u) {
  float lo = h2f(u & 0xffffu);
  float hi = h2f(u >> 16);
  return lo * lo + hi * hi;
}
__device__ __forceinline__ void async_ld16(const void* g, const void* l) {
  __builtin_amdgcn_global_load_lds((const __attribute__((address_space(1))) void*)g,
                                   (__attribute__((address_space(3))) void*)l,
                                   16, 0, 0);
}

// ---------------- x: fp32 -> fp16, 8 elems/thread ----------------
__global__ __launch_bounds__(256) void cvt_x(const float* __restrict__ src,
                                             unsigned short* __restrict__ dst) {
  const int i = (blockIdx.x * 256 + threadIdx.x) * 8;
  const float4 a = *(const float4*)(src + i);
  const float4 b = *(const float4*)(src + i + 4);
  uint4 o;
  o.x = pack2h(a.x, a.y); o.y = pack2h(a.z, a.w);
  o.z = pack2h(b.x, b.y); o.w = pack2h(b.z, b.w);
  *(uint4*)(dst + i) = o;
}

// ------------- weight transpose+convert: src[K][N] (fp32) -> dst[N][K] (fp16) -------------
__global__ __launch_bounds__(256) void transpose_w(const float* __restrict__ src,
                                                   unsigned short* __restrict__ dst,
                                                   int K, int N) {
  __shared__ unsigned short tile[32][33];
  const int tx = threadIdx.x, ty = threadIdx.y;           // (32,8)
  const int nb = blockIdx.x * 32, kb = blockIdx.y * 32;
#pragma unroll
  for (int i = 0; i < 4; i++)
    tile[ty + 8 * i][tx] = f2h(src[(size_t)(kb + ty + 8 * i) * N + nb + tx]);
  __syncthreads();
#pragma unroll
  for (int i = 0; i < 4; i++)
    dst[(size_t)(nb + ty + 8 * i) * K + kb + tx] = tile[tx][ty + 8 * i];
}

// ------------- C[M][N] = A[M][K] * Bt[N][K]^T + bias[N]  (fp16 in, fp32 acc) -------------
// m97 structure: 128x128 tile, BK=32, global_load_lds width=16, 4 waves 4x4 MFMA.
template <bool OUT_F32>
__global__ __launch_bounds__(256) void gemm_bt(const unsigned short* __restrict__ A,
                                               const unsigned short* __restrict__ Bt,
                                               const float* __restrict__ bias,
                                               void* __restrict__ Cp,
                                               int N, int K) {
  __shared__ __attribute__((aligned(16))) unsigned short Atile[128 * 32];
  __shared__ __attribute__((aligned(16))) unsigned short Btile[128 * 32];
  const int tid = threadIdx.x;
  const int w = tid >> 6, lane = tid & 63;
  const int quad = lane >> 4, l15 = lane & 15;
  const int m0 = blockIdx.y * 128, n0 = blockIdx.x * 128;
  const int wr = w >> 1, wc = w & 1;
  f32x4 acc[4][4] = {};
  for (int kt = 0; kt < K; kt += 32) {
    __syncthreads();  // previous iteration's fragment reads complete
#pragma unroll
    for (int it = 0; it < 2; it++) {
      const int c = it * 256 + tid;       // chunk: row = c>>2, 8-elem k-chunk = c&3
      const int row = c >> 2, kc = c & 3;
      async_ld16(A + (size_t)(m0 + row) * K + kt + kc * 8,
                 &Atile[(size_t)(it * 256 + w * 64) * 8]);   // wave-uniform LDS base
      async_ld16(Bt + (size_t)(n0 + row) * K + kt + kc * 8,
                 &Btile[(size_t)(it * 256 + w * 64) * 8]);
    }
    __syncthreads();  // vmcnt(0) drain lands the async copies
    f16x8 af[4], bfr[4];
#pragma unroll
    for (int i = 0; i < 4; i++)
      af[i] = *(const f16x8*)&Atile[(wr * 64 + i * 16 + l15) * 32 + quad * 8];
#pragma unroll
    for (int j = 0; j < 4; j++)
      bfr[j] = *(const f16x8*)&Btile[(wc * 64 + j * 16 + l15) * 32 + quad * 8];
#pragma unroll
    for (int i = 0; i < 4; i++)
#pragma unroll
      for (int j = 0; j < 4; j++)
        acc[i][j] = MFMA16(af[i], bfr[j], acc[i][j]);
  }
  // epilogue: C/D layout col=lane&15, row=quad*4+reg
#pragma unroll
  for (int j = 0; j < 4; j++) {
    const int n = n0 + wc * 64 + j * 16 + l15;
    const float bv = bias[n];
#pragma unroll
    for (int i = 0; i < 4; i++) {
      const int mb = m0 + wr * 64 + i * 16 + quad * 4;
#pragma unroll
      for (int r = 0; r < 4; r++) {
        if constexpr (OUT_F32)
          ((float*)Cp)[(size_t)(mb + r) * N + n] = acc[i][j][r] + bv;
        else
          ((unsigned short*)Cp)[(size_t)(mb + r) * N + n] = f2h(acc[i][j][r] + bv);
      }
    }
  }
}

// ---------------- Yat causal flash attention (fp16 in/out, fp32 math) ----------------
// grid: (B*H, 32). Block 256 = 4 waves; wave w owns q rows [16w,16w+16).
// score = dot^2 * rcp(qsq + ksq - 2 dot + 1e-6), causal, online softmax.
// PV as O^T = V^T * P^T (rescale per-lane uniform). K/V prefetched one
// iteration ahead in registers; Vt staged via transposed u32 loads + 2x b128.
__global__ __launch_bounds__(256, 4) void yat_attn(const unsigned short* __restrict__ qkv,
                                                   unsigned short* __restrict__ outp) {
  __shared__ __attribute__((aligned(16))) unsigned short Qp[64 * 72];  // [q][d] pad 72
  __shared__ __attribute__((aligned(16))) unsigned short Kp[64 * 72];  // [t][d]
  __shared__ __attribute__((aligned(16))) unsigned short Vt[64 * 72];  // [d][t]
  __shared__ __attribute__((aligned(16))) unsigned short Pl[64 * 72];  // [q][t]
  __shared__ float qsq[64], ksq[64], bcast[64];
  const int tid = threadIdx.x;
  const int w = tid >> 6, lane = tid & 63;
  const int quad = lane >> 4, l15 = lane & 15;
  const int bh = blockIdx.x, b = bh >> 4, h = bh & 15;
  // dispatch-round-aware qt map: with x-fastest dispatch each CU gets one block
  // per y-octave; iteration sums per CU = (32-k)+(k+1)+(24-k)+(9+k) = 66 for all k.
  const int y = blockIdx.y;
  const int qt = (y < 8) ? 31 - y : (y < 16) ? y - 8 : (y < 24) ? 39 - y : y - 16;
  const unsigned short* base = qkv + (size_t)b * TSEQ * 3072 + h * 64;
  const int t = tid >> 2, dc = (tid & 3) * 16;   // K/Q staging: row t, 16 d's
  const int d0 = tid & 31, tg8 = tid >> 5;       // V staging: 2 d-rows, 8 t's

  {  // stage Q tile + row sums of squares (same rounded values MFMA sees)
    const unsigned short* g = base + (size_t)(qt * 64 + t) * 3072 + dc;
    uint4 v0 = *(const uint4*)g;
    uint4 v1 = *(const uint4*)(g + 8);
    *(uint4*)&Qp[t * 72 + dc] = v0;
    *(uint4*)&Qp[t * 72 + dc + 8] = v1;
    float s = sumsq_u32(v0.x) + sumsq_u32(v0.y) + sumsq_u32(v0.z) + sumsq_u32(v0.w) +
              sumsq_u32(v1.x) + sumsq_u32(v1.y) + sumsq_u32(v1.z) + sumsq_u32(v1.w);
    s += __shfl_xor(s, 1);
    s += __shfl_xor(s, 2);
    if ((tid & 3) == 0) qsq[t] = s;
  }

  f32x4 accO[4] = {};                    // O^T: lane q = 16w+l15, d = 16i+quad*4+r
  float m_r[4] = {0.f, 0.f, 0.f, 0.f};   // scores >= 0 so 0 is a valid init max
  float l_r[4] = {0.f, 0.f, 0.f, 0.f};

  // prefetch kt=0 K/V into registers
  uint4 kreg0, kreg1;
  unsigned int vreg[8];
  {
    const unsigned short* gk = base + 1024 + (size_t)t * 3072 + dc;
    kreg0 = *(const uint4*)gk;
    kreg1 = *(const uint4*)(gk + 8);
    const unsigned short* gv = base + 2048 + (size_t)(tg8 * 8) * 3072 + 2 * d0;
#pragma unroll
    for (int s = 0; s < 8; s++)
      vreg[s] = *(const unsigned int*)(gv + (size_t)s * 3072);
  }

  for (int kt = 0; kt <= qt; kt++) {
    __syncthreads();  // prev iteration's Kp/Vt/Pl reads complete
    {  // commit staged K [t][d] + ksq from registers
      *(uint4*)&Kp[t * 72 + dc] = kreg0;
      *(uint4*)&Kp[t * 72 + dc + 8] = kreg1;
      float s = sumsq_u32(kreg0.x) + sumsq_u32(kreg0.y) + sumsq_u32(kreg0.z) +
                sumsq_u32(kreg0.w) + sumsq_u32(kreg1.x) + sumsq_u32(kreg1.y) +
                sumsq_u32(kreg1.z) + sumsq_u32(kreg1.w);
      s += __shfl_xor(s, 1);
      s += __shfl_xor(s, 2);
      if ((tid & 3) == 0) ksq[t] = s;
      // commit V^T [d][t]: repack 8 transposed u32 -> 2x ds_write_b128
      uint4 LO, HI;
      LO.x = (vreg[0] & 0xffffu) | (vreg[1] << 16);
      LO.y = (vreg[2] & 0xffffu) | (vreg[3] << 16);
      LO.z = (vreg[4] & 0xffffu) | (vreg[5] << 16);
      LO.w = (vreg[6] & 0xffffu) | (vreg[7] << 16);
      HI.x = (vreg[0] >> 16) | (vreg[1] & 0xffff0000u);
      HI.y = (vreg[2] >> 16) | (vreg[3] & 0xffff0000u);
      HI.z = (vreg[4] >> 16) | (vreg[5] & 0xffff0000u);
      HI.w = (vreg[6] >> 16) | (vreg[7] & 0xffff0000u);
      *(uint4*)&Vt[(2 * d0) * 72 + tg8 * 8] = LO;
      *(uint4*)&Vt[(2 * d0 + 1) * 72 + tg8 * 8] = HI;
    }
    if (kt < qt) {  // prefetch kt+1 — latency overlaps this iteration's compute
      const unsigned short* gk = base + 1024 + (size_t)((kt + 1) * 64 + t) * 3072 + dc;
      kreg0 = *(const uint4*)gk;
      kreg1 = *(const uint4*)(gk + 8);
      const unsigned short* gv =
          base + 2048 + (size_t)((kt + 1) * 64 + tg8 * 8) * 3072 + 2 * d0;
#pragma unroll
      for (int s = 0; s < 8; s++)
        vreg[s] = *(const unsigned int*)(gv + (size_t)s * 3072);
    }
    __syncthreads();  // staging visible

    // S = Q K^T : wave's 16 q rows x 64 keys
    f32x4 accS[4] = {};
    const f16x8 aq0 = *(const f16x8*)&Qp[(w * 16 + l15) * 72 + quad * 8];
    const f16x8 aq1 = *(const f16x8*)&Qp[(w * 16 + l15) * 72 + 32 + quad * 8];
#pragma unroll
    for (int nt = 0; nt < 4; nt++) {
      const f16x8 bk0 = *(const f16x8*)&Kp[(nt * 16 + l15) * 72 + quad * 8];
      const f16x8 bk1 = *(const f16x8*)&Kp[(nt * 16 + l15) * 72 + 32 + quad * 8];
      accS[nt] = MFMA16(aq0, bk0, accS[nt]);
      accS[nt] = MFMA16(aq1, bk1, accS[nt]);
    }
    const bool diag = (kt == qt);
    float pval[4][4];
    float tmax[4] = {0.f, 0.f, 0.f, 0.f};  // scores >= 0
#pragma unroll
    for (int nt = 0; nt < 4; nt++) {
#pragma unroll
      for (int r = 0; r < 4; r++) {
        const int ql = w * 16 + quad * 4 + r;   // C-layout row
        const int tl = nt * 16 + l15;           // C-layout col
        const float d = accS[nt][r];
        const float den = qsq[ql] + ksq[tl] - 2.f * d + 1e-6f;
        float s = d * d * __builtin_amdgcn_rcpf(den);
        if (diag && tl > ql) s = -1e30f;
        pval[nt][r] = s;
        tmax[r] = fmaxf(tmax[r], s);
      }
    }
#pragma unroll
    for (int r = 0; r < 4; r++) {
      tmax[r] = fmaxf(tmax[r], __shfl_xor(tmax[r], 1));
      tmax[r] = fmaxf(tmax[r], __shfl_xor(tmax[r], 2));
      tmax[r] = fmaxf(tmax[r], __shfl_xor(tmax[r], 4));
      tmax[r] = fmaxf(tmax[r], __shfl_xor(tmax[r], 8));
    }
    float alpha[4];
#pragma unroll
    for (int r = 0; r < 4; r++) {
      const float mn = fmaxf(m_r[r], tmax[r]);
      alpha[r] = __expf(m_r[r] - mn);
      m_r[r] = mn;
    }
#pragma unroll
    for (int nt = 0; nt < 4; nt++)
#pragma unroll
      for (int r = 0; r < 4; r++)
        pval[nt][r] = __expf(pval[nt][r] - m_r[r]);
#pragma unroll
    for (int r = 0; r < 4; r++) {
      float su = pval[0][r] + pval[1][r] + pval[2][r] + pval[3][r];
      su += __shfl_xor(su, 1);
      su += __shfl_xor(su, 2);
      su += __shfl_xor(su, 4);
      su += __shfl_xor(su, 8);
      l_r[r] = l_r[r] * alpha[r] + su;
    }
#pragma unroll
    for (int nt = 0; nt < 4; nt++)
#pragma unroll
      for (int r = 0; r < 4; r++)
        Pl[(w * 16 + quad * 4 + r) * 72 + nt * 16 + l15] = f2h(pval[nt][r]);
    if (l15 == 0) {
#pragma unroll
      for (int r = 0; r < 4; r++) bcast[w * 16 + quad * 4 + r] = alpha[r];
    }
    __syncthreads();  // Pl/bcast visible

    // rescale O^T (per-lane uniform alpha) then O^T += V^T P^T
    const float am = bcast[w * 16 + l15];
#pragma unroll
    for (int i = 0; i < 4; i++) {
      accO[i][0] *= am; accO[i][1] *= am; accO[i][2] *= am; accO[i][3] *= am;
    }
    const f16x8 bp0 = *(const f16x8*)&Pl[(w * 16 + l15) * 72 + quad * 8];
    const f16x8 bp1 = *(const f16x8*)&Pl[(w * 16 + l15) * 72 + 32 + quad * 8];
#pragma unroll
    for (int i = 0; i < 4; i++) {
      const f16x8 av0 = *(const f16x8*)&Vt[(i * 16 + l15) * 72 + quad * 8];
      const f16x8 av1 = *(const f16x8*)&Vt[(i * 16 + l15) * 72 + 32 + quad * 8];
      accO[i] = MFMA16(av0, bp0, accO[i]);
      accO[i] = MFMA16(av1, bp1, accO[i]);
    }
  }

  // finalize: divide by l, transpose O^T -> O through LDS, coalesced 16B stores
  __syncthreads();
  if (l15 == 0) {
#pragma unroll
    for (int r = 0; r < 4; r++) bcast[w * 16 + quad * 4 + r] = l_r[r];
  }
  __syncthreads();
  const float linv = 1.0f / bcast[w * 16 + l15];
#pragma unroll
  for (int i = 0; i < 4; i++)
#pragma unroll
    for (int r = 0; r < 4; r++)
      Qp[(w * 16 + l15) * 72 + i * 16 + quad * 4 + r] = f2h(accO[i][r] * linv);
  __syncthreads();
  {
    uint4 o0 = *(const uint4*)&Qp[t * 72 + dc];
    uint4 o1 = *(const uint4*)&Qp[t * 72 + dc + 8];
    unsigned short* g = outp + (size_t)(b * TSEQ + qt * 64 + t) * 1024 + h * 64 + dc;
    *(uint4*)g = o0;
    *(uint4*)(g + 8) = o1;
  }
}

extern "C" void kernel_launch(void* const* d_in, const int* in_sizes, int n_in,
                              void* d_out, int out_size, void* d_ws, size_t ws_size,
                              hipStream_t stream) {
  (void)in_sizes; (void)n_in; (void)out_size; (void)ws_size;
  const float* x     = (const float*)d_in[0];  // [2,2048,1024] fp32
  const float* w_qkv = (const float*)d_in[1];  // [1024,3072]   fp32
  const float* b_qkv = (const float*)d_in[2];  // [3072]        fp32
  const float* w_out = (const float*)d_in[3];  // [1024,1024]   fp32
  const float* b_out = (const float*)d_in[4];  // [1024]        fp32
  float* out = (float*)d_out;                  // [2,2048,1024] fp32

  unsigned short* wqkvT  = (unsigned short*)d_ws;                    // [3072][1024] fp16
  unsigned short* woT    = wqkvT + (size_t)3072 * 1024;              // [1024][1024] fp16
  unsigned short* qkvws  = woT + (size_t)1024 * 1024;                // [4096][3072] fp16
  unsigned short* xh     = qkvws + (size_t)4096 * 3072;              // [4096][1024] fp16
  unsigned short* attnws = xh;  // alias: xh dead after gemm1, attnws born at yat_attn

  cvt_x<<<dim3(4096 * 1024 / (256 * 8)), 256, 0, stream>>>(x, xh);
  transpose_w<<<dim3(3072 / 32, 1024 / 32), dim3(32, 8), 0, stream>>>(w_qkv, wqkvT, 1024, 3072);
  transpose_w<<<dim3(1024 / 32, 1024 / 32), dim3(32, 8), 0, stream>>>(w_out, woT, 1024, 1024);
  gemm_bt<false><<<dim3(3072 / 128, 4096 / 128), 256, 0, stream>>>(xh, wqkvT, b_qkv, qkvws, 3072, 1024);
  yat_attn<<<dim3(BATCH * 16, 32), 256, 0, stream>>>(qkvws, attnws);
  gemm_bt<true><<<dim3(1024 / 128, 4096 / 128), 256, 0, stream>>>(attnws, woT, b_out, out, 1024, 1024);
}